// Round 6
// baseline (258.214 us; speedup 1.0000x reference)
//
#include <hip/hip_runtime.h>

typedef __attribute__((ext_vector_type(8))) short bf16x8;
typedef __attribute__((ext_vector_type(4))) float f32x4;
typedef unsigned short ushort_t;
typedef unsigned int uint_t;

// Hardware bf16 conversion: scalar __bf16 casts compile to v_cvt_pk_bf16_f32
// on gfx950 (learn_hip m240: compiler fuses pairs; RNE).
__device__ __forceinline__ ushort_t f2bf(float f) {
    return __builtin_bit_cast(ushort_t, (__bf16)f);
}
__device__ __forceinline__ uint_t pack2(float a, float b) {
    return (uint_t)f2bf(a) | ((uint_t)f2bf(b) << 16);
}

#define LOG2E 1.4426950408889634f

// ---------------- workspace layout (ushort elements) ----------------
#define WT_OFF   0
#define WOT_OFF  524288
#define QKV_OFF  655360
#define QKV_SZ   2097152
#define QKV_OFF_Z3 (3 * (size_t)QKV_SZ)
#define O_OFF    9043968

// ---------------- weight transpose + fp32->bf16 (coalesced, LDS tile) --------
__global__ __launch_bounds__(256) void transpose_w(
    const float* __restrict__ Wq, const float* __restrict__ Wq2,
    const float* __restrict__ Wk, const float* __restrict__ Wv,
    const float* __restrict__ Wo, ushort_t* __restrict__ ws)
{
    __shared__ ushort_t lT[64][72];
    const int j = blockIdx.y;
    const int bx = blockIdx.x;
    const float* in;
    ushort_t* out;
    int C;
    if (j < 4) {
        in = (j == 0) ? Wq : (j == 1) ? Wq2 : (j == 2) ? Wk : Wv;
        out = ws + WT_OFF + (size_t)j * 131072; C = 256;
    } else {
        in = Wo; out = ws + WOT_OFF; C = 512;
    }
    const int R = 131072 / C;
    const int tc = C >> 6;
    const int r0 = (bx / tc) * 64, c0 = (bx % tc) * 64;
    const int t = threadIdx.x;
    const int ir = t >> 4, ic = (t & 15) * 4;
#pragma unroll
    for (int i = 0; i < 4; ++i) {
        const int r = ir + i * 16;
        float4 v = *(const float4*)(in + (size_t)(r0 + r) * C + c0 + ic);
        uint2 w; w.x = pack2(v.x, v.y); w.y = pack2(v.z, v.w);
        *(uint2*)&lT[r][ic] = w;
    }
    __syncthreads();
    const int oc = t >> 2, rr0 = (t & 3) * 16;
    ushort_t g[16];
#pragma unroll
    for (int k = 0; k < 16; ++k) g[k] = lT[rr0 + k][oc];
    ushort_t* op = out + (size_t)(c0 + oc) * R + r0 + rr0;
    *(uint4*)op = *(const uint4*)&g[0];
    *(uint4*)(op + 8) = *(const uint4*)&g[8];
}

// ---------------- projections: 64x256 tile per block (R1-verified) ----------
#define PROJ_STAGE(K0, BUF) do {                                                     \
    _Pragma("unroll")                                                                \
    for (int it_ = 0; it_ < 4; ++it_) {                                              \
        const int p_ = tid + it_ * 256;                                              \
        const ushort_t* bp_ = Bt + (size_t)(p_ >> 2) * 512 + (K0) + ((p_ & 3) << 3); \
        __builtin_amdgcn_global_load_lds(                                            \
            (const __attribute__((address_space(1))) void*)bp_,                      \
            (__attribute__((address_space(3))) void*)&lB[BUF][p_ * 8], 16, 0, 0);    \
    }                                                                                \
} while (0)

__global__ __launch_bounds__(256) void proj_gemm(
    const float* __restrict__ x1, const float* __restrict__ x2,
    const float* __restrict__ ctx, const ushort_t* __restrict__ Wt,
    ushort_t* __restrict__ QKV)
{
    __shared__ __align__(16) ushort_t lB[2][256 * 32];
    const int z = blockIdx.y;
    const float* A = (z == 0) ? x1 : (z == 1) ? x2 : ctx;
    const ushort_t* Bt = Wt + (size_t)z * 131072;
    const float sc = (z < 2) ? (0.125f * LOG2E) : 1.0f;
    const int tid = threadIdx.x;
    const int wave = tid >> 6, lane = tid & 63;
    const int quad = lane >> 4, l16 = lane & 15;
    const size_t row0 = (size_t)blockIdx.x * 64;

    PROJ_STAGE(0, 0);

    const float* arow = A + (row0 + wave * 16 + l16) * 512 + quad * 8;
    float4 a0 = *(const float4*)(arow);
    float4 a1 = *(const float4*)(arow + 4);

    f32x4 acc[16] = {};
    for (int k0 = 0; k0 < 512; k0 += 32) {
        const int pb = (k0 >> 5) & 1;
        __syncthreads();
        if (k0 + 32 < 512) PROJ_STAGE(k0 + 32, 1 - pb);
        float4 n0 = a0, n1 = a1;
        if (k0 + 32 < 512) {
            n0 = *(const float4*)(arow + k0 + 32);
            n1 = *(const float4*)(arow + k0 + 36);
        }
        uint4 aw;
        aw.x = pack2(a0.x, a0.y); aw.y = pack2(a0.z, a0.w);
        aw.z = pack2(a1.x, a1.y); aw.w = pack2(a1.z, a1.w);
        bf16x8 af = __builtin_bit_cast(bf16x8, aw);
#pragma unroll
        for (int c = 0; c < 16; ++c) {
            bf16x8 bfr = *(const bf16x8*)&lB[pb][(c * 16 + l16) * 32 + quad * 8];
            acc[c] = __builtin_amdgcn_mfma_f32_16x16x32_bf16(af, bfr, acc[c], 0, 0, 0);
        }
        a0 = n0; a1 = n1;
    }

    if (z == 3) {
        const int b = (int)(row0 >> 11);
        const int tokl = ((int)row0 & 2047) + wave * 16 + quad * 4;
        ushort_t* Vt = QKV + QKV_OFF_Z3;
#pragma unroll
        for (int c = 0; c < 16; ++c) {
            const int col = c * 16 + l16;
            const int h = col >> 6, d = col & 63;
            uint2 w;
            w.x = pack2(acc[c][0], acc[c][1]);
            w.y = pack2(acc[c][2], acc[c][3]);
            *(uint2*)(Vt + ((size_t)((b * 4 + h) * 64 + d)) * 2048 + tokl) = w;
        }
    } else {
        ushort_t* C = QKV + (size_t)z * QKV_SZ;
#pragma unroll
        for (int c = 0; c < 16; ++c) {
            const int col = c * 16 + l16;
#pragma unroll
            for (int r = 0; r < 4; ++r)
                C[(row0 + wave * 16 + quad * 4 + r) * 256 + col] = f2bf(acc[c][r] * sc);
        }
    }
}

// ---------------- output projection: 64x128 tile (R1-verified) ---------------
#define OUT_STAGE(K0, BUF) do {                                                      \
    _Pragma("unroll")                                                                \
    for (int it_ = 0; it_ < 2; ++it_) {                                              \
        const int p_ = tid + it_ * 256;                                              \
        const ushort_t* bp_ = Wot + (size_t)(col0 + (p_ >> 2)) * 256 + (K0) + ((p_ & 3) << 3); \
        __builtin_amdgcn_global_load_lds(                                            \
            (const __attribute__((address_space(1))) void*)bp_,                      \
            (__attribute__((address_space(3))) void*)&lB[BUF][p_ * 8], 16, 0, 0);    \
    }                                                                                \
} while (0)

__global__ __launch_bounds__(256) void out_gemm(
    const ushort_t* __restrict__ Op, const ushort_t* __restrict__ Wot,
    const float* __restrict__ bias, float* __restrict__ out)
{
    __shared__ __align__(16) ushort_t lB[2][128 * 32];
    const int tid = threadIdx.x;
    const int wave = tid >> 6, lane = tid & 63;
    const int quad = lane >> 4, l16 = lane & 15;
    const size_t row0 = (size_t)blockIdx.x * 64;
    const int col0 = blockIdx.y * 128;

    OUT_STAGE(0, 0);
    const ushort_t* arow = Op + (row0 + wave * 16 + l16) * 256 + quad * 8;
    bf16x8 af = *(const bf16x8*)(arow);

    f32x4 acc[8] = {};
    for (int k0 = 0; k0 < 256; k0 += 32) {
        const int pb = (k0 >> 5) & 1;
        __syncthreads();
        if (k0 + 32 < 256) OUT_STAGE(k0 + 32, 1 - pb);
        bf16x8 an = af;
        if (k0 + 32 < 256) an = *(const bf16x8*)(arow + k0 + 32);
#pragma unroll
        for (int c = 0; c < 8; ++c) {
            bf16x8 bfr = *(const bf16x8*)&lB[pb][(c * 16 + l16) * 32 + quad * 8];
            acc[c] = __builtin_amdgcn_mfma_f32_16x16x32_bf16(af, bfr, acc[c], 0, 0, 0);
        }
        af = an;
    }
#pragma unroll
    for (int c = 0; c < 8; ++c) {
        const int col = col0 + c * 16 + l16;
        const float bv = bias[col];
#pragma unroll
        for (int r = 0; r < 4; ++r)
            out[(row0 + wave * 16 + quad * 4 + r) * 512 + col] = acc[c][r] + bv;
    }
}

// ---------------- fused dual-softmax flash attention ----------------
// K/V fragments read DIRECTLY from global (L2-resident streams; 32 blocks
// share each head). No lK/lV, no global_load_lds, NO BARRIERS — each wave
// independent. LDS keeps only the per-wave lP quad-redistribution (R4 code).
// T15: PV(i-1) issued at iter top, overlapping QK(i)+sm(i).
// Fragment identity (swizzle cancelled): kf[c][ks] = K[tok0+i*64+c*16+l16]
// [in0+(ks*4+quad)*8]; vf[c][ks] = Vt[bh64+c*16+l16][i*64+(ks*4+quad)*8].

#define ATTN_QK_SM(I) do {                                                              \
    bf16x8 kf[4][2];                                                                    \
    _Pragma("unroll")                                                                   \
    for (int c = 0; c < 4; ++c)                                                         \
        _Pragma("unroll")                                                               \
        for (int ks = 0; ks < 2; ++ks)                                                  \
            kf[c][ks] = *(const bf16x8*)(Kbase + (size_t)((I) * 64 + c * 16) * 256 + ks * 32); \
    f32x4 st1[4] = {}, st2[4] = {};                                                     \
    _Pragma("unroll")                                                                   \
    for (int c = 0; c < 4; ++c) {                                                       \
        _Pragma("unroll")                                                               \
        for (int ks = 0; ks < 2; ++ks) {                                                \
            st1[c] = __builtin_amdgcn_mfma_f32_16x16x32_bf16(kf[c][ks], q1f[ks], st1[c], 0, 0, 0); \
            st2[c] = __builtin_amdgcn_mfma_f32_16x16x32_bf16(kf[c][ks], q2f[ks], st2[c], 0, 0, 0); \
        } }                                                                             \
    _Pragma("unroll")                                                                   \
    for (int c = 0; c < 4; ++c) {                                                       \
        float p0 = __builtin_amdgcn_exp2f(st1[c][0]);                                   \
        float p1 = __builtin_amdgcn_exp2f(st1[c][1]);                                   \
        float p2 = __builtin_amdgcn_exp2f(st1[c][2]);                                   \
        float p3 = __builtin_amdgcn_exp2f(st1[c][3]);                                   \
        l1 += (p0 + p1) + (p2 + p3);                                                    \
        uint2 w; w.x = pack2(p0, p1); w.y = pack2(p2, p3);                              \
        *(uint2*)&lPw0[l16 * 72 + c * 16 + quad * 4] = w;                               \
        float r0 = __builtin_amdgcn_exp2f(st2[c][0]);                                   \
        float r1 = __builtin_amdgcn_exp2f(st2[c][1]);                                   \
        float r2 = __builtin_amdgcn_exp2f(st2[c][2]);                                   \
        float r3 = __builtin_amdgcn_exp2f(st2[c][3]);                                   \
        l2 += (r0 + r1) + (r2 + r3);                                                    \
        uint2 y; y.x = pack2(r0, r1); y.y = pack2(r2, r3);                              \
        *(uint2*)&lPw1[l16 * 72 + c * 16 + quad * 4] = y;                               \
    }                                                                                   \
    _Pragma("unroll")                                                                   \
    for (int ks = 0; ks < 2; ++ks) {                                                    \
        pa1[ks] = *(const bf16x8*)&lPw0[l16 * 72 + ks * 32 + quad * 8];                 \
        pa2[ks] = *(const bf16x8*)&lPw1[l16 * 72 + ks * 32 + quad * 8];                 \
    }                                                                                   \
} while (0)

#define ATTN_PV(I) do {                                                                 \
    _Pragma("unroll")                                                                   \
    for (int c = 0; c < 4; ++c) {                                                       \
        _Pragma("unroll")                                                               \
        for (int ks = 0; ks < 2; ++ks) {                                                \
            bf16x8 vf = *(const bf16x8*)(Vbase + (size_t)(c * 16) * 2048 + (I) * 64 + ks * 32); \
            o1[c] = __builtin_amdgcn_mfma_f32_16x16x32_bf16(vf, pa1[ks], o1[c], 0, 0, 0); \
            o2[c] = __builtin_amdgcn_mfma_f32_16x16x32_bf16(vf, pa2[ks], o2[c], 0, 0, 0); \
        } }                                                                             \
} while (0)

__global__ __launch_bounds__(256) void attn_fused(
    const ushort_t* __restrict__ Qb, const ushort_t* __restrict__ Q2b,
    const ushort_t* __restrict__ Kb, const ushort_t* __restrict__ Vt,
    ushort_t* __restrict__ Ob)
{
    __shared__ __align__(16) ushort_t lP[4][2][16 * 72];

    const int qt = blockIdx.x;
    const int bh = blockIdx.y;
    const int tid = threadIdx.x;
    const int wave = tid >> 6, lane = tid & 63;
    const int quad = lane >> 4, l16 = lane & 15;
    const size_t tok0 = (size_t)(bh >> 2) * 2048;
    const int in0 = (bh & 3) * 64;
    const int bh64 = bh * 64;
    ushort_t* lPw0 = &lP[wave][0][0];
    ushort_t* lPw1 = &lP[wave][1][0];

    // Q fragments: direct global load (B-operand layout is row-contiguous 16B)
    bf16x8 q1f[2], q2f[2];
    {
        const ushort_t* qr1 = Qb  + (tok0 + qt * 64 + wave * 16 + l16) * 256 + in0;
        const ushort_t* qr2 = Q2b + (tok0 + qt * 64 + wave * 16 + l16) * 256 + in0;
#pragma unroll
        for (int ks = 0; ks < 2; ++ks) {
            q1f[ks] = *(const bf16x8*)(qr1 + ks * 32 + quad * 8);
            q2f[ks] = *(const bf16x8*)(qr2 + ks * 32 + quad * 8);
        }
    }

    // direct-global fragment bases (per-lane)
    const ushort_t* Kbase = Kb + (tok0 + l16) * 256 + in0 + quad * 8;
    const ushort_t* Vbase = Vt + ((size_t)(bh64 + l16)) * 2048 + quad * 8;

    f32x4 o1[4] = {}, o2[4] = {};
    bf16x8 pa1[2], pa2[2];
    float l1 = 0.f, l2 = 0.f;

    ATTN_QK_SM(0);
    for (int i = 1; i < 32; ++i) {
        ATTN_PV(i - 1);      // consumes pa from iter i-1 before sm(i) overwrites
        ATTN_QK_SM(i);
    }
    ATTN_PV(31);

    // l reduction across quads (lanes with same l16)
    l1 += __shfl_xor(l1, 16, 64); l1 += __shfl_xor(l1, 32, 64);
    l2 += __shfl_xor(l2, 16, 64); l2 += __shfl_xor(l2, 32, 64);
    const float inv1 = 0.3f / l1, inv2 = 0.7f / l2;

    // O^T C-layout: row d = c*16 + quad*4 + r, col q = l16 (this wave's 16 q-rows)
    ushort_t* orow = Ob + (tok0 + qt * 64 + wave * 16 + l16) * 256 + in0;
#pragma unroll
    for (int c = 0; c < 4; ++c) {
        const float f0 = o1[c][0] * inv1 + o2[c][0] * inv2;
        const float f1 = o1[c][1] * inv1 + o2[c][1] * inv2;
        const float f2 = o1[c][2] * inv1 + o2[c][2] * inv2;
        const float f3 = o1[c][3] * inv1 + o2[c][3] * inv2;
        uint2 w; w.x = pack2(f0, f1); w.y = pack2(f2, f3);
        *(uint2*)(orow + c * 16 + quad * 4) = w;
    }
}

// ---------------- launch ----------------
extern "C" void kernel_launch(void* const* d_in, const int* in_sizes, int n_in,
                              void* d_out, int out_size, void* d_ws, size_t ws_size,
                              hipStream_t stream)
{
    (void)in_sizes; (void)n_in; (void)out_size; (void)ws_size;
    const float* x1  = (const float*)d_in[0];
    const float* x2  = (const float*)d_in[1];
    const float* ctx = (const float*)d_in[2];
    const float* Wq  = (const float*)d_in[3];
    const float* Wq2 = (const float*)d_in[4];
    const float* Wk  = (const float*)d_in[5];
    const float* Wv  = (const float*)d_in[6];
    const float* Wo  = (const float*)d_in[7];
    const float* bo  = (const float*)d_in[8];
    ushort_t* ws  = (ushort_t*)d_ws;
    float* out = (float*)d_out;

    ushort_t* Wt  = ws + WT_OFF;
    ushort_t* Wot = ws + WOT_OFF;
    ushort_t* QKV = ws + QKV_OFF;
    ushort_t* Q   = QKV;
    ushort_t* Q2  = QKV + 1 * (size_t)QKV_SZ;
    ushort_t* Kp  = QKV + 2 * (size_t)QKV_SZ;
    ushort_t* Vt  = QKV + 3 * (size_t)QKV_SZ;
    ushort_t* Op  = ws + O_OFF;

    transpose_w<<<dim3(32, 5),  256, 0, stream>>>(Wq, Wq2, Wk, Wv, Wo, ws);
    proj_gemm  <<<dim3(128, 4), 256, 0, stream>>>(x1, x2, ctx, Wt, QKV);
    attn_fused <<<dim3(32, 16), 256, 0, stream>>>(Q, Q2, Kp, Vt, Op);
    out_gemm   <<<dim3(128, 4), 256, 0, stream>>>(Op, Wot, bo, out);
}

// Round 7
// 170.060 us; speedup vs baseline: 1.5184x; 1.5184x over previous
//
#include <hip/hip_runtime.h>

typedef __attribute__((ext_vector_type(8))) short bf16x8;
typedef __attribute__((ext_vector_type(4))) float f32x4;
typedef unsigned short ushort_t;
typedef unsigned int uint_t;

// Hardware bf16 conversion: scalar __bf16 casts compile to v_cvt_pk_bf16_f32
// on gfx950 (learn_hip m240: compiler fuses pairs; RNE).
__device__ __forceinline__ ushort_t f2bf(float f) {
    return __builtin_bit_cast(ushort_t, (__bf16)f);
}
__device__ __forceinline__ uint_t pack2(float a, float b) {
    return (uint_t)f2bf(a) | ((uint_t)f2bf(b) << 16);
}

#define LOG2E 1.4426950408889634f

// ---------------- workspace layout (ushort elements) ----------------
#define WT_OFF   0
#define WOT_OFF  524288
#define QKV_OFF  655360
#define QKV_SZ   2097152
#define QKV_OFF_Z3 (3 * (size_t)QKV_SZ)
#define O_OFF    9043968

// ---------------- weight transpose + fp32->bf16 (coalesced, LDS tile) --------
__global__ __launch_bounds__(256) void transpose_w(
    const float* __restrict__ Wq, const float* __restrict__ Wq2,
    const float* __restrict__ Wk, const float* __restrict__ Wv,
    const float* __restrict__ Wo, ushort_t* __restrict__ ws)
{
    __shared__ ushort_t lT[64][72];
    const int j = blockIdx.y;
    const int bx = blockIdx.x;
    const float* in;
    ushort_t* out;
    int C;
    if (j < 4) {
        in = (j == 0) ? Wq : (j == 1) ? Wq2 : (j == 2) ? Wk : Wv;
        out = ws + WT_OFF + (size_t)j * 131072; C = 256;
    } else {
        in = Wo; out = ws + WOT_OFF; C = 512;
    }
    const int R = 131072 / C;
    const int tc = C >> 6;
    const int r0 = (bx / tc) * 64, c0 = (bx % tc) * 64;
    const int t = threadIdx.x;
    const int ir = t >> 4, ic = (t & 15) * 4;
#pragma unroll
    for (int i = 0; i < 4; ++i) {
        const int r = ir + i * 16;
        float4 v = *(const float4*)(in + (size_t)(r0 + r) * C + c0 + ic);
        uint2 w; w.x = pack2(v.x, v.y); w.y = pack2(v.z, v.w);
        *(uint2*)&lT[r][ic] = w;
    }
    __syncthreads();
    const int oc = t >> 2, rr0 = (t & 3) * 16;
    ushort_t g[16];
#pragma unroll
    for (int k = 0; k < 16; ++k) g[k] = lT[rr0 + k][oc];
    ushort_t* op = out + (size_t)(c0 + oc) * R + r0 + rr0;
    *(uint4*)op = *(const uint4*)&g[0];
    *(uint4*)(op + 8) = *(const uint4*)&g[8];
}

// ---------------- projections: 64x256 tile per block, BK=64 ------------------
// B-tile [256 rows][64 k] in LDS, 128B rows, attn-verified XOR swizzle:
// stage source group g=(cc^(cc>>3))&7 (linear dest), read group
// (ks*4+quad)^(l16&7) -> conflict-free b128 reads (was ~8-way at 64B rows).
#define PROJ_STAGE(K0, BUF) do {                                                     \
    _Pragma("unroll")                                                                \
    for (int it_ = 0; it_ < 8; ++it_) {                                              \
        const int cc_ = tid + it_ * 256;                                             \
        const int g_ = (cc_ ^ (cc_ >> 3)) & 7;                                       \
        const ushort_t* bp_ = Bt + (size_t)(cc_ >> 3) * 512 + (K0) + g_ * 8;         \
        __builtin_amdgcn_global_load_lds(                                            \
            (const __attribute__((address_space(1))) void*)bp_,                      \
            (__attribute__((address_space(3))) void*)&lB[BUF][cc_ * 8], 16, 0, 0);   \
    }                                                                                \
} while (0)

__global__ __launch_bounds__(256) void proj_gemm(
    const float* __restrict__ x1, const float* __restrict__ x2,
    const float* __restrict__ ctx, const ushort_t* __restrict__ Wt,
    ushort_t* __restrict__ QKV)
{
    __shared__ __align__(16) ushort_t lB[2][256 * 64];
    const int z = blockIdx.y;
    const float* A = (z == 0) ? x1 : (z == 1) ? x2 : ctx;
    const ushort_t* Bt = Wt + (size_t)z * 131072;
    const float sc = (z < 2) ? (0.125f * LOG2E) : 1.0f;
    const int tid = threadIdx.x;
    const int wave = tid >> 6, lane = tid & 63;
    const int quad = lane >> 4, l16 = lane & 15;
    const int l7 = l16 & 7;
    const size_t row0 = (size_t)blockIdx.x * 64;

    PROJ_STAGE(0, 0);

    const float* arow = A + (row0 + wave * 16 + l16) * 512 + quad * 8;
    float4 a[4];
    a[0] = *(const float4*)(arow);
    a[1] = *(const float4*)(arow + 4);
    a[2] = *(const float4*)(arow + 32);
    a[3] = *(const float4*)(arow + 36);

    f32x4 acc[16] = {};
    for (int k0 = 0; k0 < 512; k0 += 64) {
        const int pb = (k0 >> 6) & 1;
        __syncthreads();                     // drains staged gll for buffer pb
        if (k0 + 64 < 512) PROJ_STAGE(k0 + 64, 1 - pb);
        float4 n[4] = {a[0], a[1], a[2], a[3]};
        if (k0 + 64 < 512) {
            n[0] = *(const float4*)(arow + k0 + 64);
            n[1] = *(const float4*)(arow + k0 + 68);
            n[2] = *(const float4*)(arow + k0 + 96);
            n[3] = *(const float4*)(arow + k0 + 100);
        }
        bf16x8 af[2];
#pragma unroll
        for (int ks = 0; ks < 2; ++ks) {
            uint4 aw;
            aw.x = pack2(a[2 * ks].x, a[2 * ks].y);
            aw.y = pack2(a[2 * ks].z, a[2 * ks].w);
            aw.z = pack2(a[2 * ks + 1].x, a[2 * ks + 1].y);
            aw.w = pack2(a[2 * ks + 1].z, a[2 * ks + 1].w);
            af[ks] = __builtin_bit_cast(bf16x8, aw);
        }
#pragma unroll
        for (int c = 0; c < 16; ++c) {
#pragma unroll
            for (int ks = 0; ks < 2; ++ks) {
                bf16x8 bfr = *(const bf16x8*)&lB[pb][(c * 16 + l16) * 64 +
                                                     (((ks * 4 + quad) ^ l7) << 3)];
                acc[c] = __builtin_amdgcn_mfma_f32_16x16x32_bf16(af[ks], bfr, acc[c], 0, 0, 0);
            }
        }
        a[0] = n[0]; a[1] = n[1]; a[2] = n[2]; a[3] = n[3];
    }

    if (z == 3) {
        const int b = (int)(row0 >> 11);
        const int tokl = ((int)row0 & 2047) + wave * 16 + quad * 4;
        ushort_t* Vt = QKV + QKV_OFF_Z3;
#pragma unroll
        for (int c = 0; c < 16; ++c) {
            const int col = c * 16 + l16;
            const int h = col >> 6, d = col & 63;
            uint2 w;
            w.x = pack2(acc[c][0], acc[c][1]);
            w.y = pack2(acc[c][2], acc[c][3]);
            *(uint2*)(Vt + ((size_t)((b * 4 + h) * 64 + d)) * 2048 + tokl) = w;
        }
    } else {
        ushort_t* C = QKV + (size_t)z * QKV_SZ;
#pragma unroll
        for (int c = 0; c < 16; ++c) {
            const int col = c * 16 + l16;
#pragma unroll
            for (int r = 0; r < 4; ++r)
                C[(row0 + wave * 16 + quad * 4 + r) * 256 + col] = f2bf(acc[c][r] * sc);
        }
    }
}

// ---------------- output projection: 64x128 tile, BK=64 ----------------------
#define OUT_STAGE(K0, BUF) do {                                                      \
    _Pragma("unroll")                                                                \
    for (int it_ = 0; it_ < 4; ++it_) {                                              \
        const int cc_ = tid + it_ * 256;                                             \
        const int g_ = (cc_ ^ (cc_ >> 3)) & 7;                                       \
        const ushort_t* bp_ = Wot + (size_t)(col0 + (cc_ >> 3)) * 256 + (K0) + g_ * 8; \
        __builtin_amdgcn_global_load_lds(                                            \
            (const __attribute__((address_space(1))) void*)bp_,                      \
            (__attribute__((address_space(3))) void*)&lB[BUF][cc_ * 8], 16, 0, 0);   \
    }                                                                                \
} while (0)

__global__ __launch_bounds__(256) void out_gemm(
    const ushort_t* __restrict__ Op, const ushort_t* __restrict__ Wot,
    const float* __restrict__ bias, float* __restrict__ out)
{
    __shared__ __align__(16) ushort_t lB[2][128 * 64];
    const int tid = threadIdx.x;
    const int wave = tid >> 6, lane = tid & 63;
    const int quad = lane >> 4, l16 = lane & 15;
    const int l7 = l16 & 7;
    const size_t row0 = (size_t)blockIdx.x * 64;
    const int col0 = blockIdx.y * 128;

    OUT_STAGE(0, 0);
    const ushort_t* arow = Op + (row0 + wave * 16 + l16) * 256 + quad * 8;
    bf16x8 af0 = *(const bf16x8*)(arow);
    bf16x8 af1 = *(const bf16x8*)(arow + 32);

    f32x4 acc[8] = {};
    for (int k0 = 0; k0 < 256; k0 += 64) {
        const int pb = (k0 >> 6) & 1;
        __syncthreads();
        if (k0 + 64 < 256) OUT_STAGE(k0 + 64, 1 - pb);
        bf16x8 an0 = af0, an1 = af1;
        if (k0 + 64 < 256) {
            an0 = *(const bf16x8*)(arow + k0 + 64);
            an1 = *(const bf16x8*)(arow + k0 + 96);
        }
#pragma unroll
        for (int c = 0; c < 8; ++c) {
            bf16x8 b0 = *(const bf16x8*)&lB[pb][(c * 16 + l16) * 64 + ((quad ^ l7) << 3)];
            acc[c] = __builtin_amdgcn_mfma_f32_16x16x32_bf16(af0, b0, acc[c], 0, 0, 0);
            bf16x8 b1 = *(const bf16x8*)&lB[pb][(c * 16 + l16) * 64 + (((4 + quad) ^ l7) << 3)];
            acc[c] = __builtin_amdgcn_mfma_f32_16x16x32_bf16(af1, b1, acc[c], 0, 0, 0);
        }
        af0 = an0; af1 = an1;
    }
#pragma unroll
    for (int c = 0; c < 8; ++c) {
        const int col = col0 + c * 16 + l16;
        const float bv = bias[col];
#pragma unroll
        for (int r = 0; r < 4; ++r)
            out[(row0 + wave * 16 + quad * 4 + r) * 512 + col] = acc[c][r] + bv;
    }
}

// ---------------- fused dual-softmax flash attention (R4-verified, 56us) -----
// S^T = K·Q^T, static-max (p = exp2(s) raw), O^T = V^T·P^T.
// 3-buffer K/V rotation; per iter: QK(i) + PV(i-1) MFMA streams issue back-to-
// back, exp/pack(i) (TRANS/VALU) overlaps them; pa fragments carried in regs
// across the barrier. Buffer roles rotate prefetch->compute->PV-read.
// K LDS: [ktok][64 d], 16B-groups XOR-swizzled; V^T LDS: [d][64 tok], same.

#define ATTN_STAGE(MB, KDST, VDST) do {                                                 \
    _Pragma("unroll")                                                                   \
    for (int it_ = 0; it_ < 2; ++it_) {                                                 \
        const int cc_ = tid + it_ * 256;                                                \
        const int g_ = (cc_ ^ (cc_ >> 3)) & 7;                                          \
        const ushort_t* kp_ = Kb + (size_t)(tok0 + (MB) + (cc_ >> 3)) * 256 + in0 + g_ * 8; \
        __builtin_amdgcn_global_load_lds(                                               \
            (const __attribute__((address_space(1))) void*)kp_,                         \
            (__attribute__((address_space(3))) void*)&(KDST)[cc_ * 8], 16, 0, 0);       \
        const ushort_t* vp_ = Vt + (size_t)(bh64 + (cc_ >> 3)) * 2048 + (MB) + g_ * 8;  \
        __builtin_amdgcn_global_load_lds(                                               \
            (const __attribute__((address_space(1))) void*)vp_,                         \
            (__attribute__((address_space(3))) void*)&(VDST)[cc_ * 8], 16, 0, 0);       \
    }                                                                                   \
} while (0)

__global__ __launch_bounds__(256) void attn_fused(
    const ushort_t* __restrict__ Qb, const ushort_t* __restrict__ Q2b,
    const ushort_t* __restrict__ Kb, const ushort_t* __restrict__ Vt,
    ushort_t* __restrict__ Ob)
{
    __shared__ __align__(16) ushort_t lK[3][64 * 64];
    __shared__ __align__(16) ushort_t lV[3][64 * 64];
    __shared__ __align__(16) ushort_t lP[4][2][16 * 72];

    const int qt = blockIdx.x;
    const int bh = blockIdx.y;
    const int tid = threadIdx.x;
    const int wave = tid >> 6, lane = tid & 63;
    const int quad = lane >> 4, l16 = lane & 15;
    const int l7 = l16 & 7;
    const size_t tok0 = (size_t)(bh >> 2) * 2048;
    const int in0 = (bh & 3) * 64;
    const int bh64 = bh * 64;
    ushort_t* lPw0 = &lP[wave][0][0];
    ushort_t* lPw1 = &lP[wave][1][0];

    // Q fragments: direct global load (B-operand layout is row-contiguous 16B)
    bf16x8 q1f[2], q2f[2];
    {
        const ushort_t* qr1 = Qb  + (tok0 + qt * 64 + wave * 16 + l16) * 256 + in0;
        const ushort_t* qr2 = Q2b + (tok0 + qt * 64 + wave * 16 + l16) * 256 + in0;
#pragma unroll
        for (int ks = 0; ks < 2; ++ks) {
            q1f[ks] = *(const bf16x8*)(qr1 + ks * 32 + quad * 8);
            q2f[ks] = *(const bf16x8*)(qr2 + ks * 32 + quad * 8);
        }
    }

    // buffer role rotation: pre (prefetch target) -> cur (compute) -> old (PV)
    ushort_t* pKcur = &lK[0][0]; ushort_t* pVcur = &lV[0][0];
    ushort_t* pKpre = &lK[1][0]; ushort_t* pVpre = &lV[1][0];
    ushort_t* pKold = &lK[2][0]; ushort_t* pVold = &lV[2][0];

    ATTN_STAGE(0, pKcur, pVcur);

    f32x4 o1[4] = {}, o2[4] = {};
    bf16x8 pa1[2], pa2[2];
    float l1 = 0.f, l2 = 0.f;

    for (int i = 0; i < 32; ++i) {
        __syncthreads();                       // drains prefetch of cur tile
        if (i < 31) ATTN_STAGE((i + 1) * 64, pKpre, pVpre);

        // QK(i): S^T fragments from cur K tile
        f32x4 st1[4] = {}, st2[4] = {};
#pragma unroll
        for (int c = 0; c < 4; ++c) {
#pragma unroll
            for (int ks = 0; ks < 2; ++ks) {
                bf16x8 kf = *(const bf16x8*)&pKcur[(c * 16 + l16) * 64 +
                                                   ((((ks * 4 + quad) ^ l7) & 7) << 3)];
                st1[c] = __builtin_amdgcn_mfma_f32_16x16x32_bf16(kf, q1f[ks], st1[c], 0, 0, 0);
                st2[c] = __builtin_amdgcn_mfma_f32_16x16x32_bf16(kf, q2f[ks], st2[c], 0, 0, 0);
            }
        }

        // PV(i-1): independent of sm(i); fills matrix pipe while exp runs
        if (i > 0) {
#pragma unroll
            for (int c = 0; c < 4; ++c) {
#pragma unroll
                for (int ks = 0; ks < 2; ++ks) {
                    bf16x8 vf = *(const bf16x8*)&pVold[(c * 16 + l16) * 64 +
                                                       ((((ks * 4 + quad) ^ l7) & 7) << 3)];
                    o1[c] = __builtin_amdgcn_mfma_f32_16x16x32_bf16(vf, pa1[ks], o1[c], 0, 0, 0);
                    o2[c] = __builtin_amdgcn_mfma_f32_16x16x32_bf16(vf, pa2[ks], o2[c], 0, 0, 0);
                }
            }
        }

        // sm(i): exp2, row-sum, pack to bf16, LDS quad-redistribution
#pragma unroll
        for (int c = 0; c < 4; ++c) {
            float p0 = __builtin_amdgcn_exp2f(st1[c][0]);
            float p1 = __builtin_amdgcn_exp2f(st1[c][1]);
            float p2 = __builtin_amdgcn_exp2f(st1[c][2]);
            float p3 = __builtin_amdgcn_exp2f(st1[c][3]);
            l1 += (p0 + p1) + (p2 + p3);
            uint2 w; w.x = pack2(p0, p1); w.y = pack2(p2, p3);
            *(uint2*)&lPw0[l16 * 72 + c * 16 + quad * 4] = w;
            float r0 = __builtin_amdgcn_exp2f(st2[c][0]);
            float r1 = __builtin_amdgcn_exp2f(st2[c][1]);
            float r2 = __builtin_amdgcn_exp2f(st2[c][2]);
            float r3 = __builtin_amdgcn_exp2f(st2[c][3]);
            l2 += (r0 + r1) + (r2 + r3);
            uint2 y; y.x = pack2(r0, r1); y.y = pack2(r2, r3);
            *(uint2*)&lPw1[l16 * 72 + c * 16 + quad * 4] = y;
        }
#pragma unroll
        for (int ks = 0; ks < 2; ++ks) {
            pa1[ks] = *(const bf16x8*)&lPw0[l16 * 72 + ks * 32 + quad * 8];
            pa2[ks] = *(const bf16x8*)&lPw1[l16 * 72 + ks * 32 + quad * 8];
        }

        // rotate buffer roles: old->pre, cur->old, pre->cur
        ushort_t* tK = pKold; pKold = pKcur; pKcur = pKpre; pKpre = tK;
        ushort_t* tV = pVold; pVold = pVcur; pVcur = pVpre; pVpre = tV;
    }

    // final PV(31): tile 31 is in 'old' slot after the last rotation
#pragma unroll
    for (int c = 0; c < 4; ++c) {
#pragma unroll
        for (int ks = 0; ks < 2; ++ks) {
            bf16x8 vf = *(const bf16x8*)&pVold[(c * 16 + l16) * 64 +
                                               ((((ks * 4 + quad) ^ l7) & 7) << 3)];
            o1[c] = __builtin_amdgcn_mfma_f32_16x16x32_bf16(vf, pa1[ks], o1[c], 0, 0, 0);
            o2[c] = __builtin_amdgcn_mfma_f32_16x16x32_bf16(vf, pa2[ks], o2[c], 0, 0, 0);
        }
    }

    // l reduction across quads (lanes with same l16)
    l1 += __shfl_xor(l1, 16, 64); l1 += __shfl_xor(l1, 32, 64);
    l2 += __shfl_xor(l2, 16, 64); l2 += __shfl_xor(l2, 32, 64);
    const float inv1 = 0.3f / l1, inv2 = 0.7f / l2;

    // O^T C-layout: row d = c*16 + quad*4 + r, col q = l16 (this wave's 16 q-rows)
    ushort_t* orow = Ob + (tok0 + qt * 64 + wave * 16 + l16) * 256 + in0;
#pragma unroll
    for (int c = 0; c < 4; ++c) {
        const float f0 = o1[c][0] * inv1 + o2[c][0] * inv2;
        const float f1 = o1[c][1] * inv1 + o2[c][1] * inv2;
        const float f2 = o1[c][2] * inv1 + o2[c][2] * inv2;
        const float f3 = o1[c][3] * inv1 + o2[c][3] * inv2;
        uint2 w; w.x = pack2(f0, f1); w.y = pack2(f2, f3);
        *(uint2*)(orow + c * 16 + quad * 4) = w;
    }
}

// ---------------- launch ----------------
extern "C" void kernel_launch(void* const* d_in, const int* in_sizes, int n_in,
                              void* d_out, int out_size, void* d_ws, size_t ws_size,
                              hipStream_t stream)
{
    (void)in_sizes; (void)n_in; (void)out_size; (void)ws_size;
    const float* x1  = (const float*)d_in[0];
    const float* x2  = (const float*)d_in[1];
    const float* ctx = (const float*)d_in[2];
    const float* Wq  = (const float*)d_in[3];
    const float* Wq2 = (const float*)d_in[4];
    const float* Wk  = (const float*)d_in[5];
    const float* Wv  = (const float*)d_in[6];
    const float* Wo  = (const float*)d_in[7];
    const float* bo  = (const float*)d_in[8];
    ushort_t* ws  = (ushort_t*)d_ws;
    float* out = (float*)d_out;

    ushort_t* Wt  = ws + WT_OFF;
    ushort_t* Wot = ws + WOT_OFF;
    ushort_t* QKV = ws + QKV_OFF;
    ushort_t* Q   = QKV;
    ushort_t* Q2  = QKV + 1 * (size_t)QKV_SZ;
    ushort_t* Kp  = QKV + 2 * (size_t)QKV_SZ;
    ushort_t* Vt  = QKV + 3 * (size_t)QKV_SZ;
    ushort_t* Op  = ws + O_OFF;

    transpose_w<<<dim3(32, 5),  256, 0, stream>>>(Wq, Wq2, Wk, Wv, Wo, ws);
    proj_gemm  <<<dim3(128, 4), 256, 0, stream>>>(x1, x2, ctx, Wt, QKV);
    attn_fused <<<dim3(32, 16), 256, 0, stream>>>(Q, Q2, Kp, Vt, Op);
    out_gemm   <<<dim3(128, 4), 256, 0, stream>>>(Op, Wot, bo, out);
}